// Round 4
// baseline (394.537 us; speedup 1.0000x reference)
//
#include <hip/hip_runtime.h>
#include <hip/hip_bf16.h>
#include <math.h>

typedef float floatx4 __attribute__((ext_vector_type(4)));
typedef short shortx8 __attribute__((ext_vector_type(8)));
typedef unsigned short ush;
typedef ush ushx4 __attribute__((ext_vector_type(4)));

// Problem constants
#define NB    2
#define NC    512
#define NL    4096   // H*W
#define NN    1024   // (H/2)*(W/2)
#define NH    8
#define NDK   64
#define NR    63
#define LOG2E 1.44269504f
#define QT_SCALE (1.44269504f/4096.0f)

// ws layout (float offsets); total 12,587,136 f = 50.3 MB
#define OFF_Q      0u          // fp32 q (dead after off1) -> reused by ao/smp
#define OFF_AO     0u          // bf16 ao: 4,194,304 ush = 2,097,152 f
#define OFF_SMP    2097152u    // bf16 smp: 1,048,576 ush = 524,288 f
#define OFF_QT     4194304u    // bf16 qT: 4,194,304 ush = 2,097,152 f
#define OFF_T      6291456u    // fp32 t: 1,048,576 f
#define OFF_GS     7340032u    // 128
#define OFF_POS    7340160u    // 4,096
#define OFF_KT     7344256u    // bf16 kT: 1,048,576 ush = 524,288 f
#define OFF_VV     7868544u    // bf16 vv: 1,048,576 ush = 524,288 f
#define OFF_PART   8392832u    // fp32 part: 4,194,304 f
#define OFF_TAB2   8392832u    // u32 tab2: 8*4096*4B (aliases part; part dead first)

__device__ __forceinline__ ush f2bf(float f) {
    unsigned u = __float_as_uint(f);
    u += 0x7fffu + ((u >> 16) & 1u);
    return (ush)(u >> 16);
}
__device__ __forceinline__ float bf2f(ush h) {
    return __uint_as_float(((unsigned)h) << 16);
}

// ---------------------------------------------------------------------------
// Unified bf16-MFMA GEMM:  Y[b][m][p] = (bias[m]) + sum_k A[m][k] * B[b][k][p]
// NP: 1 = plain bf16; 3 = bf16x3 split precision (~fp32 accuracy)
// BSRC: 0 = fp32 [b][K][P] (float4 staging); 1 = fp32 im2col of q (2x2 s2 conv,
//        float4 covers both kw taps); 2 = bf16 [b][K][P] (8B raw copy)
// OUTMODE: 0 = fp32+bias; 2 = fp32 split-K partial (no bias);
//          3 = fp32+bias AND bf16 qT transpose [b][h][p][d] scaled by QT_SCALE;
//          4 = kv split: m<512 -> kT [b][h][p][d] bf16; m>=512 -> vv [b][c][p] bf16
// Tile 128m x 64p, BK=64, 4 waves. Fragment map (verified):
// A frag: a[m=l15][k=kk*32+quad*8]; B frag: b[p=l15][k=...]; C: row=quad*4+reg, col=l15.
// ---------------------------------------------------------------------------
template<int NP, int BSRC, int OUTMODE>
__global__ __launch_bounds__(256) void gemm_mfma_k(
    const float* __restrict__ A, const void* __restrict__ Bv,
    const float* __restrict__ bias, void* __restrict__ Yv, void* __restrict__ Y2,
    int M, int K, int P, int KS)
{
    __shared__ ush a_hi[128 * 72];
    __shared__ ush b_hi[64 * 72];
    __shared__ ush a_lo[NP == 3 ? 128 * 72 : 64];
    __shared__ ush b_lo[NP == 3 ? 64 * 72 : 64];

    int tid = threadIdx.x;
    int wv = tid >> 6, lane = tid & 63, quad = lane >> 4, l15 = lane & 15;
    int bz = blockIdx.z;
    int b = bz / KS, ks = bz - b * KS;
    int m0 = blockIdx.y * 128, p0 = blockIdx.x * 64;
    int Ksl = K / KS, kbeg = ks * Ksl;

    floatx4 acc[2][4];
    #pragma unroll
    for (int mt = 0; mt < 2; ++mt)
        #pragma unroll
        for (int pt = 0; pt < 4; ++pt) acc[mt][pt] = (floatx4)0.f;

    for (int kc = 0; kc < Ksl; kc += 64) {
        int kg0 = kbeg + kc;
        #pragma unroll
        for (int r = 0; r < 8; ++r) {
            int idx = r * 256 + tid;
            int m = idx >> 4, k4 = (idx & 15) << 2;
            float4 av = *(const float4*)(A + (size_t)(m0 + m) * K + kg0 + k4);
            int o = m * 72 + k4;
            ush h0 = f2bf(av.x), h1 = f2bf(av.y), h2 = f2bf(av.z), h3 = f2bf(av.w);
            a_hi[o] = h0; a_hi[o + 1] = h1; a_hi[o + 2] = h2; a_hi[o + 3] = h3;
            if (NP == 3) {
                a_lo[o]     = f2bf(av.x - bf2f(h0));
                a_lo[o + 1] = f2bf(av.y - bf2f(h1));
                a_lo[o + 2] = f2bf(av.z - bf2f(h2));
                a_lo[o + 3] = f2bf(av.w - bf2f(h3));
            }
        }
        // B staging: 4 iters x 256 thr x 4 elements = 4096 = 64k x 64p
        #pragma unroll
        for (int r = 0; r < 4; ++r) {
            int e = r * 256 + tid;
            if (BSRC == 1) {
                // e -> k-pair (32) x p-pair (32); float4 covers kw=0/1, ow/ow+1
                int k2 = e >> 5;            // local k pair: kl = 2*k2, 2*k2+1
                int p2 = (e & 31) << 1;     // even p
                int kk = kg0 + (k2 << 1);
                int c = kk >> 2, kh = (kk >> 1) & 1;
                int p = p0 + p2, oh = p >> 5, ow = p & 31;
                const float* Bp = (const float*)Bv + (size_t)b * NC * NL;
                float4 av = *(const float4*)(Bp + (size_t)c * NL + (2 * oh + kh) * 64 + 2 * ow);
                int kl = k2 << 1;
                ush h0 = f2bf(av.x), h1 = f2bf(av.y), h2 = f2bf(av.z), h3 = f2bf(av.w);
                b_hi[p2 * 72 + kl]           = h0;
                b_hi[p2 * 72 + kl + 1]       = h1;
                b_hi[(p2 + 1) * 72 + kl]     = h2;
                b_hi[(p2 + 1) * 72 + kl + 1] = h3;
                if (NP == 3) {
                    b_lo[p2 * 72 + kl]           = f2bf(av.x - bf2f(h0));
                    b_lo[p2 * 72 + kl + 1]       = f2bf(av.y - bf2f(h1));
                    b_lo[(p2 + 1) * 72 + kl]     = f2bf(av.z - bf2f(h2));
                    b_lo[(p2 + 1) * 72 + kl + 1] = f2bf(av.w - bf2f(h3));
                }
            } else if (BSRC == 0) {
                int k = e >> 4, p4 = (e & 15) << 2;
                const float* Bp = (const float*)Bv + (size_t)b * K * P;
                float4 av = *(const float4*)(Bp + (size_t)(kg0 + k) * P + p0 + p4);
                ush h0 = f2bf(av.x), h1 = f2bf(av.y), h2 = f2bf(av.z), h3 = f2bf(av.w);
                b_hi[p4 * 72 + k]       = h0;
                b_hi[(p4 + 1) * 72 + k] = h1;
                b_hi[(p4 + 2) * 72 + k] = h2;
                b_hi[(p4 + 3) * 72 + k] = h3;
                if (NP == 3) {
                    b_lo[p4 * 72 + k]       = f2bf(av.x - bf2f(h0));
                    b_lo[(p4 + 1) * 72 + k] = f2bf(av.y - bf2f(h1));
                    b_lo[(p4 + 2) * 72 + k] = f2bf(av.z - bf2f(h2));
                    b_lo[(p4 + 3) * 72 + k] = f2bf(av.w - bf2f(h3));
                }
            } else {
                // bf16 source: raw copy (f2bf(bf2f(h)) == h)
                int k = e >> 4, p4 = (e & 15) << 2;
                const ush* Bp = (const ush*)Bv + (size_t)b * K * P;
                ushx4 uv = *(const ushx4*)(Bp + (size_t)(kg0 + k) * P + p0 + p4);
                b_hi[p4 * 72 + k]       = uv.x;
                b_hi[(p4 + 1) * 72 + k] = uv.y;
                b_hi[(p4 + 2) * 72 + k] = uv.z;
                b_hi[(p4 + 3) * 72 + k] = uv.w;
            }
        }
        __syncthreads();

        shortx8 ah[2][2], al[2][2];
        #pragma unroll
        for (int mt = 0; mt < 2; ++mt)
            #pragma unroll
            for (int kk = 0; kk < 2; ++kk) {
                int o = (wv * 32 + mt * 16 + l15) * 72 + kk * 32 + quad * 8;
                ah[mt][kk] = *(const shortx8*)&a_hi[o];
                if (NP == 3) al[mt][kk] = *(const shortx8*)&a_lo[o];
            }
        #pragma unroll
        for (int pt = 0; pt < 4; ++pt) {
            #pragma unroll
            for (int kk = 0; kk < 2; ++kk) {
                int o = (pt * 16 + l15) * 72 + kk * 32 + quad * 8;
                shortx8 bh = *(const shortx8*)&b_hi[o];
                acc[0][pt] = __builtin_amdgcn_mfma_f32_16x16x32_bf16(ah[0][kk], bh, acc[0][pt], 0, 0, 0);
                acc[1][pt] = __builtin_amdgcn_mfma_f32_16x16x32_bf16(ah[1][kk], bh, acc[1][pt], 0, 0, 0);
                if (NP == 3) {
                    shortx8 bl = *(const shortx8*)&b_lo[o];
                    acc[0][pt] = __builtin_amdgcn_mfma_f32_16x16x32_bf16(ah[0][kk], bl, acc[0][pt], 0, 0, 0);
                    acc[1][pt] = __builtin_amdgcn_mfma_f32_16x16x32_bf16(ah[1][kk], bl, acc[1][pt], 0, 0, 0);
                    acc[0][pt] = __builtin_amdgcn_mfma_f32_16x16x32_bf16(al[0][kk], bh, acc[0][pt], 0, 0, 0);
                    acc[1][pt] = __builtin_amdgcn_mfma_f32_16x16x32_bf16(al[1][kk], bh, acc[1][pt], 0, 0, 0);
                }
            }
        }
        __syncthreads();
    }

    #pragma unroll
    for (int mt = 0; mt < 2; ++mt) {
        #pragma unroll
        for (int reg = 0; reg < 4; ++reg) {
            int m = m0 + wv * 32 + mt * 16 + quad * 4 + reg;
            float bb = (OUTMODE == 2) ? 0.f : bias[m];
            #pragma unroll
            for (int pt = 0; pt < 4; ++pt) {
                int p = p0 + pt * 16 + l15;
                float val = acc[mt][pt][reg] + bb;
                if (OUTMODE == 0) {
                    ((float*)Yv)[(size_t)b * M * P + (size_t)m * P + p] = val;
                } else if (OUTMODE == 2) {
                    ((float*)Yv)[(size_t)(ks * NB + b) * M * P + (size_t)m * P + p] = val;
                } else if (OUTMODE == 3) {
                    ((float*)Yv)[(size_t)b * M * P + (size_t)m * P + p] = val;
                    int h = m >> 6, d = m & 63;
                    ((ush*)Y2)[(((size_t)(b * 8 + h) * 4096) + p) * 64 + d] = f2bf(val * QT_SCALE);
                } else { // 4
                    if (m < 512) {
                        int h = m >> 6, d = m & 63;
                        ((ush*)Yv)[(((size_t)(b * 8 + h) * 1024) + p) * 64 + d] = f2bf(val);
                    } else {
                        int c = m - 512;
                        ((ush*)Y2)[((size_t)(b * 512) + c) * 1024 + p] = f2bf(val);
                    }
                }
            }
        }
    }
}

// ---------------------------------------------------------------------------
// split-K reduce for off1: t = sum_ks part + bias
// ---------------------------------------------------------------------------
__global__ __launch_bounds__(256) void reduce_off1_k(const float* __restrict__ part,
                                                     const float* __restrict__ bias,
                                                     float* __restrict__ t)
{
    int i = blockIdx.x * 256 + threadIdx.x;
    float v = part[i] + part[i + 1048576] + part[i + 2097152] + part[i + 3145728];
    t[i] = v + bias[(i >> 10) & 511];
}

// ---------------------------------------------------------------------------
__global__ __launch_bounds__(256) void gn_stats_k(const float* __restrict__ T, float* __restrict__ gs)
{
    int bg = blockIdx.x;
    const float* base = T + (size_t)bg * 16384;
    float s = 0.f, ss = 0.f;
    for (int i = threadIdx.x; i < 16384; i += 256) { float v = base[i]; s += v; ss += v * v; }
    #pragma unroll
    for (int off = 32; off >= 1; off >>= 1) { s += __shfl_xor(s, off); ss += __shfl_xor(ss, off); }
    __shared__ float red[8];
    int wv = threadIdx.x >> 6;
    if ((threadIdx.x & 63) == 0) { red[wv * 2] = s; red[wv * 2 + 1] = ss; }
    __syncthreads();
    if (threadIdx.x == 0) {
        float S = red[0] + red[2] + red[4] + red[6];
        float SS = red[1] + red[3] + red[5] + red[7];
        float mu = S / 16384.f;
        float var = SS / 16384.f - mu * mu;
        gs[bg * 2] = mu;
        gs[bg * 2 + 1] = rsqrtf(var + 1e-5f);
    }
}

__global__ __launch_bounds__(256) void gn_gelu_k(float* __restrict__ T, const float* __restrict__ gs,
                                                 const float* __restrict__ gw, const float* __restrict__ gb)
{
    int idx = blockIdx.x * 256 + threadIdx.x;
    int bg = idx >> 14;
    int c = (idx >> 10) & 511;
    float mu = gs[bg * 2], rs = gs[bg * 2 + 1];
    float v = (T[idx] - mu) * rs * gw[c] + gb[c];
    T[idx] = v * 0.5f * (1.f + erff(v * 0.70710678118654752f));
}

// ---------------------------------------------------------------------------
// offset head: split-C grid. 64 blocks; block = 32 ops x 8 c-groups.
// ---------------------------------------------------------------------------
__global__ __launch_bounds__(256) void offset_pos_k(const float* __restrict__ T,
                                                    const float* __restrict__ w2,
                                                    float* __restrict__ pos)
{
    int b = blockIdx.x >> 5;
    int og = threadIdx.x & 31;
    int cg = threadIdx.x >> 5;
    int op = ((blockIdx.x & 31) << 5) + og;
    const float* Tb = T + (size_t)b * NC * NN + (size_t)cg * 64 * NN + op;
    float o0 = 0.f, o1 = 0.f;
    #pragma unroll 4
    for (int c = 0; c < 64; ++c) {
        float tv = Tb[(size_t)c * NN];
        o0 += w2[cg * 64 + c] * tv;
        o1 += w2[512 + cg * 64 + c] * tv;
    }
    __shared__ float rs[2][8][32];
    rs[0][cg][og] = o0;
    rs[1][cg][og] = o1;
    __syncthreads();
    if (threadIdx.x < 64) {
        int coord = threadIdx.x >> 5, og2 = threadIdx.x & 31;
        float s = 0.f;
        #pragma unroll
        for (int k = 0; k < 8; ++k) s += rs[coord][k][og2];
        int opf = ((blockIdx.x & 31) << 5) + og2;
        int oh = opf >> 5, ow = opf & 31;
        float ref = (coord == 0) ? ((0.5f + oh) / 31.f * 2.f - 1.f)
                                 : ((0.5f + ow) / 31.f * 2.f - 1.f);
        pos[((size_t)b * 1024 + opf) * 2 + coord] = fminf(fmaxf(s + ref, -1.f), 1.f);
    }
}

// ---------------------------------------------------------------------------
// Bilinear sample of x at pos -> smp[b][c][j] (bf16 out)
// ---------------------------------------------------------------------------
__global__ __launch_bounds__(256) void sample_k(const float* __restrict__ x,
                                                const float* __restrict__ pos,
                                                ush* __restrict__ smp)
{
    int idx = blockIdx.x * 256 + threadIdx.x;
    int j = idx & 1023, c = (idx >> 10) & 511, b = idx >> 19;
    float py = pos[(b * 1024 + j) * 2];
    float px = pos[(b * 1024 + j) * 2 + 1];
    float fx = (px + 1.f) * 0.5f * 63.f;
    float fy = (py + 1.f) * 0.5f * 63.f;
    float flx = floorf(fx), fly = floorf(fy);
    float wx = fx - flx, wy = fy - fly;
    int x0 = min(max((int)flx, 0), 63), y0 = min(max((int)fly, 0), 63);
    int x1 = min(x0 + 1, 63),           y1 = min(y0 + 1, 63);
    const float* xb = x + ((size_t)(b * NC + c)) * NL;
    float v00 = xb[y0 * 64 + x0];
    float v01 = xb[y0 * 64 + x1];
    float v10 = xb[y1 * 64 + x0];
    float v11 = xb[y1 * 64 + x1];
    float v = v00 * (1 - wx) * (1 - wy) + v01 * wx * (1 - wy)
            + v10 * (1 - wx) * wy       + v11 * wx * wy;
    smp[idx] = f2bf(v);
}

// ---------------------------------------------------------------------------
// tab2: per-head 64x64 x-pair-packed bf16 of rpe*log2e (zero-pad), with
// per-row XOR bank swizzle: logical (y,x) stored at column x ^ (y & 31).
// tab2[h][y][x^(y&31)] = pack(v(y,x), v(y,x+1)).
// ---------------------------------------------------------------------------
__global__ __launch_bounds__(256) void tab2_k(const float* __restrict__ rpe,
                                              unsigned* __restrict__ tab2)
{
    int i = blockIdx.x * 256 + threadIdx.x;   // 8*4096
    int h = i >> 12, y = (i >> 6) & 63, x = i & 63;
    const float* R = rpe + (size_t)h * 3969;
    float v0 = (y < 63 && x < 63)     ? R[y * 63 + x] * LOG2E : 0.f;
    float v1 = (y < 63 && x + 1 < 63) ? R[y * 63 + x + 1] * LOG2E : 0.f;
    int xs = x ^ (y & 31);
    tab2[(h << 12) + (y << 6) + xs] = (unsigned)f2bf(v0) | ((unsigned)f2bf(v1) << 16);
}

// ---------------------------------------------------------------------------
// MFMA flash attention, barrier-free j-loop. Block = (b,h) x 64-query tile,
// 4 waves x 16 rows. Q/K/V fragments direct from global (bf16, pre-laid-out).
// V loads hoisted ahead of the bias-eval chain (latency overlap). Bias eval:
// clamp-free (gy,gx in [0,62] by construction; row/col 63 zero-padded),
// XOR-swizzled table (bank = (x0^y0)&31 kills quad-group conflicts).
// No online max (logits ~1e-2; exp2-domain). Denom via MFMA against ones.
// LDS = 9216 (pa) + 16384 (tab2) + 8192 (posj15) = 33792 B -> 4 blocks/CU.
// ---------------------------------------------------------------------------
__global__ __launch_bounds__(256) void attn_k(
    const ush* __restrict__ qT, const ush* __restrict__ kT,
    const ush* __restrict__ vv, const float* __restrict__ pos,
    const unsigned* __restrict__ tab2, ush* __restrict__ ao)
{
    __shared__ __align__(16) char smem[33792];
    ush*      pa     = (ush*)smem;               // [64][72]    9216 B
    unsigned* tab_s  = (unsigned*)(smem + 9216); // [64][64]   16384 B
    float*    posj15 = (float*)(smem + 25600);   // [1024][2]   8192 B
    float*    obuf   = (float*)smem;             // [64][68] epilogue alias

    int bh = blockIdx.y;
    int b = bh >> 3, h = bh & 7;
    int m0 = blockIdx.x * 64;
    int tid = threadIdx.x;
    int wv = tid >> 6, lane = tid & 63, quad = lane >> 4, l15 = lane & 15;

    // Q fragments (global, issue early)
    const ush* qbase = qT + ((size_t)bh * 4096 + m0 + wv * 16 + l15) * 64 + quad * 8;
    shortx8 qf0 = *(const shortx8*)(qbase);
    shortx8 qf1 = *(const shortx8*)(qbase + 32);

    // stage tab2 (pre-swizzled) + pos*15.5
    const uint2* tg = (const uint2*)(tab2 + (size_t)h * 4096);
    uint2* tab_s2 = (uint2*)tab_s;
    for (int i = tid; i < 2048; i += 256) tab_s2[i] = tg[i];
    const float* pb = pos + (size_t)b * 2048;
    for (int i = tid; i < 2048; i += 256) posj15[i] = pb[i] * 15.5f;

    float qy15[4], qx15[4];
    #pragma unroll
    for (int reg = 0; reg < 4; ++reg) {
        int mg = m0 + wv * 16 + quad * 4 + reg;
        qy15[reg] = (float)(mg >> 6) * (31.f / 63.f) + 15.5f;
        qx15[reg] = (float)(mg & 63) * (31.f / 63.f) + 15.5f;
    }

    floatx4 o_acc[4], o_sum;
    #pragma unroll
    for (int dt = 0; dt < 4; ++dt) o_acc[dt] = (floatx4)0.f;
    o_sum = (floatx4)0.f;
    shortx8 vone = {16256, 16256, 16256, 16256, 16256, 16256, 16256, 16256};

    __syncthreads();

    const ush* kbase = kT + (size_t)bh * 1024 * 64;
    const ush* vbase = vv + (size_t)(b * 512 + h * 64) * 1024;

    for (int jc = 0; jc < 16; ++jc) {
        int j0 = jc * 64;
        // ---- QK^T (K frags from global) ----
        floatx4 sacc[4];
        #pragma unroll
        for (int jt = 0; jt < 4; ++jt) sacc[jt] = (floatx4)0.f;
        #pragma unroll
        for (int jt = 0; jt < 4; ++jt) {
            const ush* kp = kbase + (size_t)(j0 + jt * 16 + l15) * 64 + quad * 8;
            shortx8 kf0 = *(const shortx8*)kp;
            shortx8 kf1 = *(const shortx8*)(kp + 32);
            sacc[jt] = __builtin_amdgcn_mfma_f32_16x16x32_bf16(qf0, kf0, sacc[jt], 0, 0, 0);
            sacc[jt] = __builtin_amdgcn_mfma_f32_16x16x32_bf16(qf1, kf1, sacc[jt], 0, 0, 0);
        }
        // ---- V loads issued early: global latency hides under eval chain ----
        shortx8 vf[4][2];
        #pragma unroll
        for (int dt = 0; dt < 4; ++dt) {
            const ush* vp = vbase + (size_t)(dt * 16 + l15) * 1024 + j0 + quad * 8;
            vf[dt][0] = *(const shortx8*)vp;
            vf[dt][1] = *(const shortx8*)(vp + 32);
        }
        // ---- bias (2 LDS b32/eval, swizzled, clamp-free) + exp2 + P write ----
        #pragma unroll
        for (int jt = 0; jt < 4; ++jt) {
            int j = j0 + jt * 16 + l15;
            float2 pp = *(const float2*)&posj15[j * 2];
            #pragma unroll
            for (int reg = 0; reg < 4; ++reg) {
                float gy = qy15[reg] - pp.x;
                float gx = qx15[reg] - pp.y;
                int y0 = (int)gy;             // trunc == floor (gy >= 0)
                int x0 = (int)gx;
                float wy = gy - (float)y0;
                float wx = gx - (float)x0;
                int y1 = y0 + 1;
                unsigned tw0 = tab_s[(y0 << 6) + (x0 ^ (y0 & 31))];
                unsigned tw1 = tab_s[(y1 << 6) + (x0 ^ (y1 & 31))];
                float r00 = __uint_as_float(tw0 << 16);
                float r01 = __uint_as_float(tw0 & 0xffff0000u);
                float r10 = __uint_as_float(tw1 << 16);
                float r11 = __uint_as_float(tw1 & 0xffff0000u);
                float bx0 = r00 + wx * (r01 - r00);
                float bx1 = r10 + wx * (r11 - r10);
                float p = exp2f(sacc[jt][reg] + (bx0 + wy * (bx1 - bx0)));
                pa[(wv * 16 + quad * 4 + reg) * 72 + jt * 16 + l15] = f2bf(p);
            }
        }
        // ---- PV + denom (wave-private P roundtrip, no barrier) ----
        const ush* pbase = pa + (wv * 16 + l15) * 72 + quad * 8;
        shortx8 pf0 = *(const shortx8*)pbase;
        shortx8 pf1 = *(const shortx8*)(pbase + 32);
        o_sum = __builtin_amdgcn_mfma_f32_16x16x32_bf16(pf0, vone, o_sum, 0, 0, 0);
        o_sum = __builtin_amdgcn_mfma_f32_16x16x32_bf16(pf1, vone, o_sum, 0, 0, 0);
        #pragma unroll
        for (int dt = 0; dt < 4; ++dt) {
            o_acc[dt] = __builtin_amdgcn_mfma_f32_16x16x32_bf16(pf0, vf[dt][0], o_acc[dt], 0, 0, 0);
            o_acc[dt] = __builtin_amdgcn_mfma_f32_16x16x32_bf16(pf1, vf[dt][1], o_acc[dt], 0, 0, 0);
        }
    }

    // ---- epilogue: divide by denom, transpose via LDS, coalesced bf16 store ----
    __syncthreads();
    float inv[4];
    #pragma unroll
    for (int reg = 0; reg < 4; ++reg) inv[reg] = 1.f / o_sum[reg];
    #pragma unroll
    for (int dt = 0; dt < 4; ++dt)
        #pragma unroll
        for (int reg = 0; reg < 4; ++reg)
            obuf[(dt * 16 + l15) * 68 + wv * 16 + quad * 4 + reg] = o_acc[dt][reg] * inv[reg];
    __syncthreads();
    ush* aobase = ao + ((size_t)(b * 512 + h * 64)) * 4096 + m0;
    for (int i = tid; i < 4096; i += 256) {
        int d = i >> 6, m = i & 63;
        aobase[(size_t)d * 4096 + m] = f2bf(obuf[d * 68 + m]);
    }
}

// ---------------------------------------------------------------------------
extern "C" void kernel_launch(void* const* d_in, const int* in_sizes, int n_in,
                              void* d_out, int out_size, void* d_ws, size_t ws_size,
                              hipStream_t stream) {
    const float* x      = (const float*)d_in[0];
    const float* q_w    = (const float*)d_in[1];
    const float* q_b    = (const float*)d_in[2];
    const float* kv_w   = (const float*)d_in[3];
    const float* kv_b   = (const float*)d_in[4];
    const float* off1_w = (const float*)d_in[5];
    const float* off1_b = (const float*)d_in[6];
    const float* gn_w   = (const float*)d_in[7];
    const float* gn_b   = (const float*)d_in[8];
    const float* off2_w = (const float*)d_in[9];
    const float* rpe    = (const float*)d_in[10];
    const float* proj_w = (const float*)d_in[11];
    const float* proj_b = (const float*)d_in[12];

    float* ws   = (float*)d_ws;
    float* q    = ws + OFF_Q;
    ush*   ao   = (ush*)(ws + OFF_AO);
    ush*   smp  = (ush*)(ws + OFF_SMP);
    ush*   qT   = (ush*)(ws + OFF_QT);
    float* t    = ws + OFF_T;
    float* gs   = ws + OFF_GS;
    float* pos  = ws + OFF_POS;
    ush*   kT   = (ush*)(ws + OFF_KT);
    ush*   vv   = (ush*)(ws + OFF_VV);
    float* part = ws + OFF_PART;
    unsigned* tab2 = (unsigned*)(ws + OFF_TAB2);
    float* out  = (float*)d_out;

    // q = 1x1 conv(x): bf16x3 MFMA; fp32 q + bf16 qT (scaled, transposed)
    gemm_mfma_k<3, 0, 3><<<dim3(64, 4, 2), 256, 0, stream>>>(q_w, x, q_b, q, qT, 512, 512, 4096, 1);
    // t = 2x2 s2 conv(q): bf16x3 MFMA, split-K=4
    gemm_mfma_k<3, 1, 2><<<dim3(16, 4, 8), 256, 0, stream>>>(off1_w, q, nullptr, part, nullptr, 512, 2048, 1024, 4);
    reduce_off1_k<<<4096, 256, 0, stream>>>(part, off1_b, t);
    // GroupNorm + GELU
    gn_stats_k<<<64, 256, 0, stream>>>(t, gs);
    gn_gelu_k<<<4096, 256, 0, stream>>>(t, gs, gn_w, gn_b);
    // offsets -> sampling positions (fp32)
    offset_pos_k<<<64, 256, 0, stream>>>(t, off2_w, pos);
    // bias table (part is dead now; tab2 aliases it)
    tab2_k<<<128, 256, 0, stream>>>(rpe, tab2);
    // bilinear sample -> bf16
    sample_k<<<4096, 256, 0, stream>>>(x, pos, smp);
    // kv = 1x1 conv(sampled): plain bf16 MFMA -> kT (transposed) + vv
    gemm_mfma_k<1, 2, 4><<<dim3(16, 8, 2), 256, 0, stream>>>(kv_w, smp, kv_b, kT, vv, 1024, 512, 1024, 1);
    // fused MFMA flash attention -> bf16 ao
    attn_k<<<dim3(64, 16), 256, 0, stream>>>(qT, kT, vv, pos, tab2, ao);
    // final projection: plain bf16 MFMA, fp32 out
    gemm_mfma_k<1, 2, 0><<<dim3(64, 4, 2), 256, 0, stream>>>(proj_w, ao, proj_b, out, nullptr, 512, 512, 4096, 1);
}

// Round 5
// 361.236 us; speedup vs baseline: 1.0922x; 1.0922x over previous
//
#include <hip/hip_runtime.h>
#include <hip/hip_bf16.h>
#include <math.h>

typedef float floatx4 __attribute__((ext_vector_type(4)));
typedef short shortx8 __attribute__((ext_vector_type(8)));
typedef unsigned short ush;

// Problem constants
#define NB    2
#define NC    512
#define NL    4096   // H*W
#define NN    1024   // (H/2)*(W/2)
#define NH    8
#define NDK   64
#define NR    63
#define LOG2E 1.44269504f
#define QT_SCALE (1.44269504f/4096.0f)

// ws layout (float offsets); total 12,587,136 f = 50.3 MB
#define OFF_Q      0u          // fp32 q (dead after off1) -> reused by ao/smp
#define OFF_AO     0u          // bf16 ao: 4,194,304 ush = 2,097,152 f
#define OFF_SMP    2097152u    // bf16 smp: 1,048,576 ush = 524,288 f
#define OFF_QT     4194304u    // bf16 qT: 4,194,304 ush = 2,097,152 f
#define OFF_T      6291456u    // fp32 t: 1,048,576 f
#define OFF_GS     7340032u    // 128
#define OFF_POS    7340160u    // 4,096
#define OFF_KT     7344256u    // bf16 kT: 1,048,576 ush = 524,288 f
#define OFF_VV     7868544u    // bf16 vv: 1,048,576 ush = 524,288 f
#define OFF_PART   8392832u    // fp32 part: 4,194,304 f
#define OFF_TAB2   8392832u    // u32 tab2: 8*4096*4B (aliases part; part dead first)

__device__ __forceinline__ ush f2bf(float f) {
    unsigned u = __float_as_uint(f);
    u += 0x7fffu + ((u >> 16) & 1u);
    return (ush)(u >> 16);
}
__device__ __forceinline__ float bf2f(ush h) {
    return __uint_as_float(((unsigned)h) << 16);
}

// ---------------------------------------------------------------------------
// Unified bf16-MFMA GEMM:  Y[b][m][p] = (bias[m]) + sum_k A[m][k] * B[b][k][p]
// NP: 1 = plain bf16; 3 = bf16x3 split precision (~fp32 accuracy)
// BSRC: 0 = fp32 [b][K][P]; 1 = fp32 im2col of q (2x2 s2 conv); 2 = bf16 [b][K][P]
// OUTMODE: 0 = fp32+bias; 2 = fp32 split-K partial (no bias);
//          3 = fp32+bias AND bf16 qT transpose [b][h][p][d] scaled by QT_SCALE;
//          4 = kv split: m<512 -> kT [b][h][p][d] bf16; m>=512 -> vv [b][c][p] bf16
// Tile 128m x 64p, BK=64, 4 waves. (B-staging: r2 proven layout — the float4
// widening in r4 regressed ~30us via 50%-utilized coalescing on BSRC1.)
// ---------------------------------------------------------------------------
template<int NP, int BSRC, int OUTMODE>
__global__ __launch_bounds__(256) void gemm_mfma_k(
    const float* __restrict__ A, const void* __restrict__ Bv,
    const float* __restrict__ bias, void* __restrict__ Yv, void* __restrict__ Y2,
    int M, int K, int P, int KS)
{
    __shared__ ush a_hi[128 * 72];
    __shared__ ush b_hi[64 * 72];
    __shared__ ush a_lo[NP == 3 ? 128 * 72 : 64];
    __shared__ ush b_lo[NP == 3 ? 64 * 72 : 64];

    int tid = threadIdx.x;
    int wv = tid >> 6, lane = tid & 63, quad = lane >> 4, l15 = lane & 15;
    int bz = blockIdx.z;
    int b = bz / KS, ks = bz - b * KS;
    int m0 = blockIdx.y * 128, p0 = blockIdx.x * 64;
    int Ksl = K / KS, kbeg = ks * Ksl;

    floatx4 acc[2][4];
    #pragma unroll
    for (int mt = 0; mt < 2; ++mt)
        #pragma unroll
        for (int pt = 0; pt < 4; ++pt) acc[mt][pt] = (floatx4)0.f;

    for (int kc = 0; kc < Ksl; kc += 64) {
        int kg0 = kbeg + kc;
        #pragma unroll
        for (int r = 0; r < 8; ++r) {
            int idx = r * 256 + tid;
            int m = idx >> 4, k4 = (idx & 15) << 2;
            float4 av = *(const float4*)(A + (size_t)(m0 + m) * K + kg0 + k4);
            int o = m * 72 + k4;
            ush h0 = f2bf(av.x), h1 = f2bf(av.y), h2 = f2bf(av.z), h3 = f2bf(av.w);
            a_hi[o] = h0; a_hi[o + 1] = h1; a_hi[o + 2] = h2; a_hi[o + 3] = h3;
            if (NP == 3) {
                a_lo[o]     = f2bf(av.x - bf2f(h0));
                a_lo[o + 1] = f2bf(av.y - bf2f(h1));
                a_lo[o + 2] = f2bf(av.z - bf2f(h2));
                a_lo[o + 3] = f2bf(av.w - bf2f(h3));
            }
        }
        #pragma unroll
        for (int r = 0; r < 8; ++r) {
            int idx = r * 256 + tid;
            int k = idx >> 5, p2 = (idx & 31) << 1;
            float v0, v1;
            if (BSRC == 0) {
                const float* Bp = (const float*)Bv + (size_t)b * K * P;
                float2 t2 = *(const float2*)(Bp + (size_t)(kg0 + k) * P + p0 + p2);
                v0 = t2.x; v1 = t2.y;
            } else if (BSRC == 1) {
                const float* Bp = (const float*)Bv + (size_t)b * NC * NL;
                int kk = kg0 + k;
                int c = kk >> 2, kh = (kk >> 1) & 1, kw = kk & 1;
                int p = p0 + p2;
                int oh = p >> 5, ow = p & 31;
                const float* base = Bp + (size_t)c * NL + (2 * oh + kh) * 64 + kw;
                v0 = base[2 * ow];
                v1 = base[2 * ow + 2];
            } else {
                const ush* Bp = (const ush*)Bv + (size_t)b * K * P;
                unsigned u = *(const unsigned*)(Bp + (size_t)(kg0 + k) * P + p0 + p2);
                v0 = bf2f((ush)(u & 0xffffu));
                v1 = bf2f((ush)(u >> 16));
            }
            ush h0 = f2bf(v0), h1 = f2bf(v1);
            b_hi[p2 * 72 + k] = h0;
            b_hi[(p2 + 1) * 72 + k] = h1;
            if (NP == 3) {
                b_lo[p2 * 72 + k]       = f2bf(v0 - bf2f(h0));
                b_lo[(p2 + 1) * 72 + k] = f2bf(v1 - bf2f(h1));
            }
        }
        __syncthreads();

        shortx8 ah[2][2], al[2][2];
        #pragma unroll
        for (int mt = 0; mt < 2; ++mt)
            #pragma unroll
            for (int kk = 0; kk < 2; ++kk) {
                int o = (wv * 32 + mt * 16 + l15) * 72 + kk * 32 + quad * 8;
                ah[mt][kk] = *(const shortx8*)&a_hi[o];
                if (NP == 3) al[mt][kk] = *(const shortx8*)&a_lo[o];
            }
        #pragma unroll
        for (int pt = 0; pt < 4; ++pt) {
            #pragma unroll
            for (int kk = 0; kk < 2; ++kk) {
                int o = (pt * 16 + l15) * 72 + kk * 32 + quad * 8;
                shortx8 bh = *(const shortx8*)&b_hi[o];
                acc[0][pt] = __builtin_amdgcn_mfma_f32_16x16x32_bf16(ah[0][kk], bh, acc[0][pt], 0, 0, 0);
                acc[1][pt] = __builtin_amdgcn_mfma_f32_16x16x32_bf16(ah[1][kk], bh, acc[1][pt], 0, 0, 0);
                if (NP == 3) {
                    shortx8 bl = *(const shortx8*)&b_lo[o];
                    acc[0][pt] = __builtin_amdgcn_mfma_f32_16x16x32_bf16(ah[0][kk], bl, acc[0][pt], 0, 0, 0);
                    acc[1][pt] = __builtin_amdgcn_mfma_f32_16x16x32_bf16(ah[1][kk], bl, acc[1][pt], 0, 0, 0);
                    acc[0][pt] = __builtin_amdgcn_mfma_f32_16x16x32_bf16(al[0][kk], bh, acc[0][pt], 0, 0, 0);
                    acc[1][pt] = __builtin_amdgcn_mfma_f32_16x16x32_bf16(al[1][kk], bh, acc[1][pt], 0, 0, 0);
                }
            }
        }
        __syncthreads();
    }

    #pragma unroll
    for (int mt = 0; mt < 2; ++mt) {
        #pragma unroll
        for (int reg = 0; reg < 4; ++reg) {
            int m = m0 + wv * 32 + mt * 16 + quad * 4 + reg;
            float bb = (OUTMODE == 2) ? 0.f : bias[m];
            #pragma unroll
            for (int pt = 0; pt < 4; ++pt) {
                int p = p0 + pt * 16 + l15;
                float val = acc[mt][pt][reg] + bb;
                if (OUTMODE == 0) {
                    ((float*)Yv)[(size_t)b * M * P + (size_t)m * P + p] = val;
                } else if (OUTMODE == 2) {
                    ((float*)Yv)[(size_t)(ks * NB + b) * M * P + (size_t)m * P + p] = val;
                } else if (OUTMODE == 3) {
                    ((float*)Yv)[(size_t)b * M * P + (size_t)m * P + p] = val;
                    int h = m >> 6, d = m & 63;
                    ((ush*)Y2)[(((size_t)(b * 8 + h) * 4096) + p) * 64 + d] = f2bf(val * QT_SCALE);
                } else { // 4
                    if (m < 512) {
                        int h = m >> 6, d = m & 63;
                        ((ush*)Yv)[(((size_t)(b * 8 + h) * 1024) + p) * 64 + d] = f2bf(val);
                    } else {
                        int c = m - 512;
                        ((ush*)Y2)[((size_t)(b * 512) + c) * 1024 + p] = f2bf(val);
                    }
                }
            }
        }
    }
}

// ---------------------------------------------------------------------------
// split-K reduce for off1: t = sum_ks part + bias
// ---------------------------------------------------------------------------
__global__ __launch_bounds__(256) void reduce_off1_k(const float* __restrict__ part,
                                                     const float* __restrict__ bias,
                                                     float* __restrict__ t)
{
    int i = blockIdx.x * 256 + threadIdx.x;
    float v = part[i] + part[i + 1048576] + part[i + 2097152] + part[i + 3145728];
    t[i] = v + bias[(i >> 10) & 511];
}

// ---------------------------------------------------------------------------
__global__ __launch_bounds__(256) void gn_stats_k(const float* __restrict__ T, float* __restrict__ gs)
{
    int bg = blockIdx.x;
    const float* base = T + (size_t)bg * 16384;
    float s = 0.f, ss = 0.f;
    for (int i = threadIdx.x; i < 16384; i += 256) { float v = base[i]; s += v; ss += v * v; }
    #pragma unroll
    for (int off = 32; off >= 1; off >>= 1) { s += __shfl_xor(s, off); ss += __shfl_xor(ss, off); }
    __shared__ float red[8];
    int wv = threadIdx.x >> 6;
    if ((threadIdx.x & 63) == 0) { red[wv * 2] = s; red[wv * 2 + 1] = ss; }
    __syncthreads();
    if (threadIdx.x == 0) {
        float S = red[0] + red[2] + red[4] + red[6];
        float SS = red[1] + red[3] + red[5] + red[7];
        float mu = S / 16384.f;
        float var = SS / 16384.f - mu * mu;
        gs[bg * 2] = mu;
        gs[bg * 2 + 1] = rsqrtf(var + 1e-5f);
    }
}

__global__ __launch_bounds__(256) void gn_gelu_k(float* __restrict__ T, const float* __restrict__ gs,
                                                 const float* __restrict__ gw, const float* __restrict__ gb)
{
    int idx = blockIdx.x * 256 + threadIdx.x;
    int bg = idx >> 14;
    int c = (idx >> 10) & 511;
    float mu = gs[bg * 2], rs = gs[bg * 2 + 1];
    float v = (T[idx] - mu) * rs * gw[c] + gb[c];
    T[idx] = v * 0.5f * (1.f + erff(v * 0.70710678118654752f));
}

// ---------------------------------------------------------------------------
// offset head: split-C grid. 64 blocks; block = 32 ops x 8 c-groups.
// ---------------------------------------------------------------------------
__global__ __launch_bounds__(256) void offset_pos_k(const float* __restrict__ T,
                                                    const float* __restrict__ w2,
                                                    float* __restrict__ pos)
{
    int b = blockIdx.x >> 5;
    int og = threadIdx.x & 31;
    int cg = threadIdx.x >> 5;
    int op = ((blockIdx.x & 31) << 5) + og;
    const float* Tb = T + (size_t)b * NC * NN + (size_t)cg * 64 * NN + op;
    float o0 = 0.f, o1 = 0.f;
    #pragma unroll 4
    for (int c = 0; c < 64; ++c) {
        float tv = Tb[(size_t)c * NN];
        o0 += w2[cg * 64 + c] * tv;
        o1 += w2[512 + cg * 64 + c] * tv;
    }
    __shared__ float rs[2][8][32];
    rs[0][cg][og] = o0;
    rs[1][cg][og] = o1;
    __syncthreads();
    if (threadIdx.x < 64) {
        int coord = threadIdx.x >> 5, og2 = threadIdx.x & 31;
        float s = 0.f;
        #pragma unroll
        for (int k = 0; k < 8; ++k) s += rs[coord][k][og2];
        int opf = ((blockIdx.x & 31) << 5) + og2;
        int oh = opf >> 5, ow = opf & 31;
        float ref = (coord == 0) ? ((0.5f + oh) / 31.f * 2.f - 1.f)
                                 : ((0.5f + ow) / 31.f * 2.f - 1.f);
        pos[((size_t)b * 1024 + opf) * 2 + coord] = fminf(fmaxf(s + ref, -1.f), 1.f);
    }
}

// ---------------------------------------------------------------------------
// Bilinear sample of x at pos -> smp[b][c][j] (bf16 out)
// ---------------------------------------------------------------------------
__global__ __launch_bounds__(256) void sample_k(const float* __restrict__ x,
                                                const float* __restrict__ pos,
                                                ush* __restrict__ smp)
{
    int idx = blockIdx.x * 256 + threadIdx.x;
    int j = idx & 1023, c = (idx >> 10) & 511, b = idx >> 19;
    float py = pos[(b * 1024 + j) * 2];
    float px = pos[(b * 1024 + j) * 2 + 1];
    float fx = (px + 1.f) * 0.5f * 63.f;
    float fy = (py + 1.f) * 0.5f * 63.f;
    float flx = floorf(fx), fly = floorf(fy);
    float wx = fx - flx, wy = fy - fly;
    int x0 = min(max((int)flx, 0), 63), y0 = min(max((int)fly, 0), 63);
    int x1 = min(x0 + 1, 63),           y1 = min(y0 + 1, 63);
    const float* xb = x + ((size_t)(b * NC + c)) * NL;
    float v00 = xb[y0 * 64 + x0];
    float v01 = xb[y0 * 64 + x1];
    float v10 = xb[y1 * 64 + x0];
    float v11 = xb[y1 * 64 + x1];
    float v = v00 * (1 - wx) * (1 - wy) + v01 * wx * (1 - wy)
            + v10 * (1 - wx) * wy       + v11 * wx * wy;
    smp[idx] = f2bf(v);
}

// ---------------------------------------------------------------------------
// tab2: per-head 64x64 x-pair-packed bf16 of rpe*log2e (zero-pad), with
// per-row XOR bank swizzle: logical (y,x) stored at column x ^ (y & 31).
// tab2[h][y][x^(y&31)] = pack(v(y,x), v(y,x+1)).
// ---------------------------------------------------------------------------
__global__ __launch_bounds__(256) void tab2_k(const float* __restrict__ rpe,
                                              unsigned* __restrict__ tab2)
{
    int i = blockIdx.x * 256 + threadIdx.x;   // 8*4096
    int h = i >> 12, y = (i >> 6) & 63, x = i & 63;
    const float* R = rpe + (size_t)h * 3969;
    float v0 = (y < 63 && x < 63)     ? R[y * 63 + x] * LOG2E : 0.f;
    float v1 = (y < 63 && x + 1 < 63) ? R[y * 63 + x + 1] * LOG2E : 0.f;
    int xs = x ^ (y & 31);
    tab2[(h << 12) + (y << 6) + xs] = (unsigned)f2bf(v0) | ((unsigned)f2bf(v1) << 16);
}

// ---------------------------------------------------------------------------
// MFMA flash attention, barrier-free j-loop. Block = (b,h) x 64-query tile,
// 4 waves x 16 rows. K software-pipelined (prefetch jc+1 after QK^T issues);
// V loads hoisted ahead of the bias-eval chain. Bias eval: clamp-free,
// qy/y0/wy hoisted per-jt (qy is block-constant), XOR-swizzled table.
// pa P-array col-swizzled (col ^ ((row>>3&1)<<4)): writes 2-way (free),
// reads stay contiguous shortx8 via eff_quad = quad ^ ((l15>>3)<<1).
// LDS = 9216 (pa) + 16384 (tab2) + 8192 (posj15) = 33792 B -> 4 blocks/CU.
// __launch_bounds__(256,4) caps VGPR at 128 to keep 4 waves/SIMD resident.
// ---------------------------------------------------------------------------
__global__ __launch_bounds__(256, 4) void attn_k(
    const ush* __restrict__ qT, const ush* __restrict__ kT,
    const ush* __restrict__ vv, const float* __restrict__ pos,
    const unsigned* __restrict__ tab2, ush* __restrict__ ao)
{
    __shared__ __align__(16) char smem[33792];
    ush*      pa     = (ush*)smem;               // [64][72]    9216 B
    unsigned* tab_s  = (unsigned*)(smem + 9216); // [64][64]   16384 B
    float*    posj15 = (float*)(smem + 25600);   // [1024][2]   8192 B
    float*    obuf   = (float*)smem;             // [64][68] epilogue alias

    int bh = blockIdx.y;
    int b = bh >> 3, h = bh & 7;
    int m0 = blockIdx.x * 64;
    int tid = threadIdx.x;
    int wv = tid >> 6, lane = tid & 63, quad = lane >> 4, l15 = lane & 15;
    int swz = (quad >> 1) & 1;                    // pa write-col swizzle bit
    int effq = quad ^ ((l15 >> 3) << 1);          // pa read quad permute

    // Q fragments (global, issue early)
    const ush* qbase = qT + ((size_t)bh * 4096 + m0 + wv * 16 + l15) * 64 + quad * 8;
    shortx8 qf0 = *(const shortx8*)(qbase);
    shortx8 qf1 = *(const shortx8*)(qbase + 32);

    // stage tab2 (pre-swizzled) + pos*15.5
    const uint2* tg = (const uint2*)(tab2 + (size_t)h * 4096);
    uint2* tab_s2 = (uint2*)tab_s;
    for (int i = tid; i < 2048; i += 256) tab_s2[i] = tg[i];
    const float* pb = pos + (size_t)b * 2048;
    for (int i = tid; i < 2048; i += 256) posj15[i] = pb[i] * 15.5f;

    // qy is block-constant (all queries in a 64-tile share m>>6)
    float qy = (float)(m0 >> 6) * (31.f / 63.f) + 15.5f;
    float qx15[4];
    #pragma unroll
    for (int reg = 0; reg < 4; ++reg)
        qx15[reg] = (float)(wv * 16 + quad * 4 + reg) * (31.f / 63.f) + 15.5f;

    floatx4 o_acc[4], o_sum;
    #pragma unroll
    for (int dt = 0; dt < 4; ++dt) o_acc[dt] = (floatx4)0.f;
    o_sum = (floatx4)0.f;
    shortx8 vone = {16256, 16256, 16256, 16256, 16256, 16256, 16256, 16256};

    const ush* kbase = kT + (size_t)bh * 1024 * 64;
    const ush* vbase = vv + (size_t)(b * 512 + h * 64) * 1024;

    // K prologue: load tile 0 fragments
    shortx8 kf0[4], kf1[4];
    #pragma unroll
    for (int jt = 0; jt < 4; ++jt) {
        const ush* kp = kbase + (size_t)(jt * 16 + l15) * 64 + quad * 8;
        kf0[jt] = *(const shortx8*)kp;
        kf1[jt] = *(const shortx8*)(kp + 32);
    }

    __syncthreads();

    int wrow = wv * 16 + quad * 4;

    for (int jc = 0; jc < 16; ++jc) {
        int j0 = jc * 64;
        // ---- QK^T with current K fragments ----
        floatx4 sacc[4];
        #pragma unroll
        for (int jt = 0; jt < 4; ++jt) sacc[jt] = (floatx4)0.f;
        #pragma unroll
        for (int jt = 0; jt < 4; ++jt) {
            sacc[jt] = __builtin_amdgcn_mfma_f32_16x16x32_bf16(qf0, kf0[jt], sacc[jt], 0, 0, 0);
            sacc[jt] = __builtin_amdgcn_mfma_f32_16x16x32_bf16(qf1, kf1[jt], sacc[jt], 0, 0, 0);
        }
        // ---- prefetch next K tile (latency hides under eval+PV) ----
        if (jc < 15) {
            #pragma unroll
            for (int jt = 0; jt < 4; ++jt) {
                const ush* kp = kbase + (size_t)(j0 + 64 + jt * 16 + l15) * 64 + quad * 8;
                kf0[jt] = *(const shortx8*)kp;
                kf1[jt] = *(const shortx8*)(kp + 32);
            }
        }
        // ---- V loads issued early: latency hides under eval chain ----
        shortx8 vf[4][2];
        #pragma unroll
        for (int dt = 0; dt < 4; ++dt) {
            const ush* vp = vbase + (size_t)(dt * 16 + l15) * 1024 + j0 + quad * 8;
            vf[dt][0] = *(const shortx8*)vp;
            vf[dt][1] = *(const shortx8*)(vp + 32);
        }
        // ---- bias eval (2 swizzled LDS b32/eval, clamp-free) + exp2 + P write ----
        #pragma unroll
        for (int jt = 0; jt < 4; ++jt) {
            int j = j0 + jt * 16 + l15;
            float2 pp = *(const float2*)&posj15[j * 2];
            float gy = qy - pp.x;
            int y0 = (int)gy;                    // trunc == floor (gy >= 0)
            float wy = gy - (float)y0;
            int rb0 = (y0 << 6), rs0 = y0 & 31;
            int rb1 = rb0 + 64,  rs1 = (y0 + 1) & 31;
            int colw = ((jt ^ swz) << 4) + l15;  // swizzled pa column
            #pragma unroll
            for (int reg = 0; reg < 4; ++reg) {
                float gx = qx15[reg] - pp.y;
                int x0 = (int)gx;
                float wx = gx - (float)x0;
                unsigned tw0 = tab_s[rb0 + (x0 ^ rs0)];
                unsigned tw1 = tab_s[rb1 + (x0 ^ rs1)];
                float r00 = __uint_as_float(tw0 << 16);
                float r01 = __uint_as_float(tw0 & 0xffff0000u);
                float r10 = __uint_as_float(tw1 << 16);
                float r11 = __uint_as_float(tw1 & 0xffff0000u);
                float bx0 = r00 + wx * (r01 - r00);
                float bx1 = r10 + wx * (r11 - r10);
                float p = exp2f(sacc[jt][reg] + (bx0 + wy * (bx1 - bx0)));
                pa[(wrow + reg) * 72 + colw] = f2bf(p);
            }
        }
        // ---- PV + denom (wave-private P roundtrip, swizzled read) ----
        const ush* pbase = pa + (wv * 16 + l15) * 72 + effq * 8;
        shortx8 pf0 = *(const shortx8*)pbase;
        shortx8 pf1 = *(const shortx8*)(pbase + 32);
        o_sum = __builtin_amdgcn_mfma_f32_16x16x32_bf16(pf0, vone, o_sum, 0, 0, 0);
        o_sum = __builtin_amdgcn_mfma_f32_16x16x32_bf16(pf1, vone, o_sum, 0, 0, 0);
        #pragma unroll
        for (int dt = 0; dt < 4; ++dt) {
            o_acc[dt] = __builtin_amdgcn_mfma_f32_16x16x32_bf16(pf0, vf[dt][0], o_acc[dt], 0, 0, 0);
            o_acc[dt] = __builtin_amdgcn_mfma_f32_16x16x32_bf16(pf1, vf[dt][1], o_acc[dt], 0, 0, 0);
        }
    }

    // ---- epilogue: divide by denom, transpose via LDS, coalesced bf16 store ----
    __syncthreads();
    float inv[4];
    #pragma unroll
    for (int reg = 0; reg < 4; ++reg) inv[reg] = 1.f / o_sum[reg];
    #pragma unroll
    for (int dt = 0; dt < 4; ++dt)
        #pragma unroll
        for (int reg = 0; reg < 4; ++reg)
            obuf[(dt * 16 + l15) * 68 + wv * 16 + quad * 4 + reg] = o_acc[dt][reg] * inv[reg];
    __syncthreads();
    ush* aobase = ao + ((size_t)(b * 512 + h * 64)) * 4096 + m0;
    for (int i = tid; i < 4096; i += 256) {
        int d = i >> 6, m = i & 63;
        aobase[(size_t)d * 4096 + m] = f2bf(obuf[d * 68 + m]);
    }
}

// ---------------------------------------------------------------------------
extern "C" void kernel_launch(void* const* d_in, const int* in_sizes, int n_in,
                              void* d_out, int out_size, void* d_ws, size_t ws_size,
                              hipStream_t stream) {
    const float* x      = (const float*)d_in[0];
    const float* q_w    = (const float*)d_in[1];
    const float* q_b    = (const float*)d_in[2];
    const float* kv_w   = (const float*)d_in[3];
    const float* kv_b   = (const float*)d_in[4];
    const float* off1_w = (const float*)d_in[5];
    const float* off1_b = (const float*)d_in[6];
    const float* gn_w   = (const float*)d_in[7];
    const float* gn_b   = (const float*)d_in[8];
    const float* off2_w = (const float*)d_in[9];
    const float* rpe    = (const float*)d_in[10];
    const float* proj_w = (const float*)d_in[11];
    const float* proj_b = (const float*)d_in[12];

    float* ws   = (float*)d_ws;
    float* q    = ws + OFF_Q;
    ush*   ao   = (ush*)(ws + OFF_AO);
    ush*   smp  = (ush*)(ws + OFF_SMP);
    ush*   qT   = (ush*)(ws + OFF_QT);
    float* t    = ws + OFF_T;
    float* gs   = ws + OFF_GS;
    float* pos  = ws + OFF_POS;
    ush*   kT   = (ush*)(ws + OFF_KT);
    ush*   vv   = (ush*)(ws + OFF_VV);
    float* part = ws + OFF_PART;
    unsigned* tab2 = (unsigned*)(ws + OFF_TAB2);
    float* out  = (float*)d_out;

    // q = 1x1 conv(x): bf16x3 MFMA; fp32 q + bf16 qT (scaled, transposed)
    gemm_mfma_k<3, 0, 3><<<dim3(64, 4, 2), 256, 0, stream>>>(q_w, x, q_b, q, qT, 512, 512, 4096, 1);
    // t = 2x2 s2 conv(q): bf16x3 MFMA, split-K=4
    gemm_mfma_k<3, 1, 2><<<dim3(16, 4, 8), 256, 0, stream>>>(off1_w, q, nullptr, part, nullptr, 512, 2048, 1024, 4);
    reduce_off1_k<<<4096, 256, 0, stream>>>(part, off1_b, t);
    // GroupNorm + GELU
    gn_stats_k<<<64, 256, 0, stream>>>(t, gs);
    gn_gelu_k<<<4096, 256, 0, stream>>>(t, gs, gn_w, gn_b);
    // offsets -> sampling positions (fp32)
    offset_pos_k<<<64, 256, 0, stream>>>(t, off2_w, pos);
    // bias table (part is dead now; tab2 aliases it)
    tab2_k<<<128, 256, 0, stream>>>(rpe, tab2);
    // bilinear sample -> bf16
    sample_k<<<4096, 256, 0, stream>>>(x, pos, smp);
    // kv = 1x1 conv(sampled): plain bf16 MFMA -> kT (transposed) + vv
    gemm_mfma_k<1, 2, 4><<<dim3(16, 8, 2), 256, 0, stream>>>(kv_w, smp, kv_b, kT, vv, 1024, 512, 1024, 1);
    // fused MFMA flash attention -> bf16 ao
    attn_k<<<dim3(64, 16), 256, 0, stream>>>(qT, kT, vv, pos, tab2, ao);
    // final projection: plain bf16 MFMA, fp32 out
    gemm_mfma_k<1, 2, 0><<<dim3(64, 4, 2), 256, 0, stream>>>(proj_w, ao, proj_b, out, nullptr, 512, 512, 4096, 1);
}